// Round 11
// baseline (159.684 us; speedup 1.0000x reference)
//
#include <hip/hip_runtime.h>

typedef __bf16 bf16_t;
typedef bf16_t bf16x8 __attribute__((ext_vector_type(8)));
typedef bf16_t bf16x4 __attribute__((ext_vector_type(4)));
typedef float  floatx4 __attribute__((ext_vector_type(4)));
typedef short  s16x4   __attribute__((ext_vector_type(4)));

#define D_MODEL 512
#define NHEAD   8
#define DK      64
#define BATCH   2
#define SEQ     2048
#define MTOT    (BATCH*SEQ)     /* 4096 */
#define QSCALE  0.18033688011112042591f  /* log2(e)/8 */

static __device__ __forceinline__ floatx4 mfma16(bf16x8 a, bf16x8 b, floatx4 c) {
    return __builtin_amdgcn_mfma_f32_16x16x32_bf16(a, b, c, 0, 0, 0);
}
// K=16 MFMA: A-operand layout k = quad*4+j == 16x16 C-layout rows -> P stays in regs
static __device__ __forceinline__ floatx4 mfma16k16(s16x4 a, s16x4 b, floatx4 c) {
    return __builtin_amdgcn_mfma_f32_16x16x16bf16_1k(a, b, c, 0, 0, 0);
}
static __device__ __forceinline__ void glds16(bf16_t* lds, const bf16_t* g) {
    __builtin_amdgcn_global_load_lds(
        (const __attribute__((address_space(1))) unsigned int*)g,
        (__attribute__((address_space(3))) unsigned int*)lds,
        16, 0, 0);
}

// ---------------------------------------------------------------------------
// Kernel 0: fp32 -> bf16 convert — PROBE: body x2 (idempotent).
// ---------------------------------------------------------------------------
__global__ __launch_bounds__(256)
void to_bf16(const float* __restrict__ x,
             const float* __restrict__ Wq, const float* __restrict__ Wk,
             const float* __restrict__ Wv, const float* __restrict__ Wo,
             bf16_t* __restrict__ xb, bf16_t* __restrict__ wqb,
             bf16_t* __restrict__ wkb, bf16_t* __restrict__ wvb,
             bf16_t* __restrict__ wob)
{
    const int blk = blockIdx.x;
    const float* src; bf16_t* dst; size_t base;
    if      (blk < 1024) { src = x;  dst = xb;  base = (size_t)blk * 2048; }
    else if (blk < 1152) { src = Wq; dst = wqb; base = (size_t)(blk - 1024) * 2048; }
    else if (blk < 1280) { src = Wk; dst = wkb; base = (size_t)(blk - 1152) * 2048; }
    else if (blk < 1408) { src = Wv; dst = wvb; base = (size_t)(blk - 1280) * 2048; }
    else                 { src = Wo; dst = wob; base = (size_t)(blk - 1408) * 2048; }
    for (int rep = 0; rep < 2; ++rep) {
        const size_t off = base + (size_t)threadIdx.x * 8;
        const float4 a = *(const float4*)(src + off);
        const float4 b = *(const float4*)(src + off + 4);
        bf16x8 p;
        p[0]=(bf16_t)a.x; p[1]=(bf16_t)a.y; p[2]=(bf16_t)a.z; p[3]=(bf16_t)a.w;
        p[4]=(bf16_t)b.x; p[5]=(bf16_t)b.y; p[6]=(bf16_t)b.z; p[7]=(bf16_t)b.w;
        const size_t off2 = off ^ ((((off >> 10) & 3)) << 3);
        *(bf16x8*)(dst + off2) = p;
        __threadfence_block();   // keep rep-2 from being optimized away
    }
}

// ---------------------------------------------------------------------------
// Kernel 1: fused QKV projection — PROBE: body x2 (idempotent).
// ---------------------------------------------------------------------------
__global__ __launch_bounds__(256)
void qkv_proj(const bf16_t* __restrict__ xb,
              const bf16_t* __restrict__ wqb, const float* __restrict__ bq,
              const bf16_t* __restrict__ wkb, const float* __restrict__ bk,
              const bf16_t* __restrict__ wvb, const float* __restrict__ bv,
              bf16_t* __restrict__ q_ws, bf16_t* __restrict__ k_ws,
              bf16_t* __restrict__ vt_ws)
{
    __shared__ bf16_t As[2][64 * 32];
    __shared__ bf16_t Bs[2][128 * 32];

    const int mtile = blockIdx.x;
    const int ntile = blockIdx.y;
    const int which = ntile >> 2;
    const int nsub  = ntile & 3;
    const bf16_t* W   = (which == 0) ? wqb : (which == 1) ? wkb : wvb;
    const float* bias = (which == 0) ? bq  : (which == 1) ? bk  : bv;

    const int tid  = threadIdx.x;
    const int lane = tid & 63;
    const int wave = tid >> 6;
    const int wm = wave & 1, wn = wave >> 1;
    const int l15 = lane & 15, quad = lane >> 4;
    const int m0 = mtile * 64;
    const int n0 = nsub * 128;
    const int lr = lane >> 2;
    const int lc = (lane & 3) * 8;
    const int csw = (quad ^ ((l15 >> 1) & 3)) * 8;

    for (int rep = 0; rep < 2; ++rep) {
        floatx4 acc[2][4] = {};

        __syncthreads();   // all waves done with LDS before restaging
        {
            glds16(&As[0][wave * 16 * 32], xb + (size_t)(m0 + wave * 16 + lr) * 512 + lc);
            #pragma unroll
            for (int q = 0; q < 2; ++q) {
                const int r = wave * 32 + q * 16;
                glds16(&Bs[0][r * 32], W + (size_t)(n0 + r + lr) * 512 + lc);
            }
        }

        for (int kk = 0; kk < 16; ++kk) {
            const int buf = kk & 1;
            __syncthreads();
            if (kk < 15) {
                const int kn = (kk + 1) * 32;
                glds16(&As[buf ^ 1][wave * 16 * 32],
                       xb + (size_t)(m0 + wave * 16 + lr) * 512 + kn + lc);
                #pragma unroll
                for (int q = 0; q < 2; ++q) {
                    const int r = wave * 32 + q * 16;
                    glds16(&Bs[buf ^ 1][r * 32], W + (size_t)(n0 + r + lr) * 512 + kn + lc);
                }
            }

            bf16x8 af[2], bfr[4];
            #pragma unroll
            for (int i = 0; i < 2; ++i)
                af[i] = *(const bf16x8*)(&As[buf][(wm * 32 + i * 16 + l15) * 32 + csw]);
            #pragma unroll
            for (int j = 0; j < 4; ++j)
                bfr[j] = *(const bf16x8*)(&Bs[buf][(wn * 64 + j * 16 + l15) * 32 + csw]);
            #pragma unroll
            for (int i = 0; i < 2; ++i)
                #pragma unroll
                for (int j = 0; j < 4; ++j)
                    acc[i][j] = mfma16(af[i], bfr[j], acc[i][j]);
        }

        #pragma unroll
        for (int j = 0; j < 4; ++j) {
            const int e = n0 + wn * 64 + j * 16 + l15;
            const float be = bias[e];
            const int h = e >> 6, d = e & 63;
            #pragma unroll
            for (int i = 0; i < 2; ++i) {
                const int mbase = m0 + wm * 32 + i * 16 + quad * 4;
                const int b = mbase >> 11;
                const int sl = mbase & 2047;
                floatx4 c = acc[i][j];
                if (which == 2) {
                    bf16x4 pk;
                    #pragma unroll
                    for (int r = 0; r < 4; ++r) pk[r] = (bf16_t)(c[r] + be);
                    const int slz = (sl & ~63) | ((((sl >> 3) & 7) ^ (d & 7)) << 3) | (sl & 7);
                    *(bf16x4*)(vt_ws + ((size_t)((b * 8 + h) * 64 + d)) * 2048 + slz) = pk;
                } else if (which == 1) {
                    #pragma unroll
                    for (int r = 0; r < 4; ++r) {
                        const int s = sl + r;
                        const int dz = ((((d >> 3) ^ (s & 7))) << 3) | (d & 7);
                        k_ws[(size_t)(b * 8 + h) * (SEQ * DK) + (size_t)s * 64 + dz] =
                            (bf16_t)(c[r] + be);
                    }
                } else {
                    #pragma unroll
                    for (int r = 0; r < 4; ++r)
                        q_ws[(size_t)(b * 8 + h) * (SEQ * DK) + (size_t)(sl + r) * 64 + d] =
                            (bf16_t)((c[r] + be) * QSCALE);
                }
            }
        }
    }
}

// ---------------------------------------------------------------------------
// Kernel 2: attention — R7 single-rep, byte-identical.
// ---------------------------------------------------------------------------
__global__ __launch_bounds__(256, 2)
void attn_kernel(const bf16_t* __restrict__ q_ws, const bf16_t* __restrict__ k_ws,
                 const bf16_t* __restrict__ vt_ws, bf16_t* __restrict__ attn_ws)
{
    __shared__ bf16_t Kt[2][2][64 * 64];
    __shared__ bf16_t Vt[2][2][64 * 64];

    const int bh = blockIdx.x;
    const int qt = blockIdx.y;
    const int tid = threadIdx.x, lane = tid & 63, wave = tid >> 6;
    const int l15 = lane & 15, quad = lane >> 4;
    const int g  = wave >> 1;
    const int wq = wave & 1;

    const bf16_t* Qb  = q_ws  + (size_t)bh * SEQ * DK;
    const bf16_t* Kb  = k_ws  + (size_t)bh * SEQ * DK;
    const bf16_t* Vtb = vt_ws + (size_t)bh * DK * SEQ;

    const int sp = wave & 1;
    const bool isK = wave < 2;
    const int srow8 = lane >> 3;
    const int scol  = (lane & 7) * 8;

    bf16x8 aq[2][2];
    #pragma unroll
    for (int mt = 0; mt < 2; ++mt)
        #pragma unroll
        for (int c = 0; c < 2; ++c)
            aq[mt][c] = *(const bf16x8*)(Qb +
                (size_t)(qt * 64 + wq * 32 + mt * 16 + l15) * 64 + c * 32 + quad * 8);

    floatx4 O[2][4] = {};
    float rs[2] = {0.f, 0.f};
    const int ksw0 = ((0 + quad) ^ (l15 & 7)) * 8;
    const int ksw1 = ((4 + quad) ^ (l15 & 7)) * 8;

    {
        const int kg = sp * 64;
        bf16_t* stile = isK ? &Kt[0][sp][0] : &Vt[0][sp][0];
        if (isK) {
            #pragma unroll
            for (int i = 0; i < 8; ++i)
                glds16(stile + i * 512, Kb + (size_t)(kg + i * 8 + srow8) * 64 + scol);
        } else {
            #pragma unroll
            for (int i = 0; i < 8; ++i)
                glds16(stile + i * 512, Vtb + (size_t)(i * 8 + srow8) * 2048 + kg + scol);
        }
    }

    for (int t = 0; t < 16; ++t) {
        const int buf = t & 1;
        __syncthreads();
        if (t < 15) {
            const int kg = (t + 1) * 128 + sp * 64;
            bf16_t* stile = isK ? &Kt[buf ^ 1][sp][0] : &Vt[buf ^ 1][sp][0];
            if (isK) {
                #pragma unroll
                for (int i = 0; i < 8; ++i)
                    glds16(stile + i * 512, Kb + (size_t)(kg + i * 8 + srow8) * 64 + scol);
            } else {
                #pragma unroll
                for (int i = 0; i < 8; ++i)
                    glds16(stile + i * 512, Vtb + (size_t)(i * 8 + srow8) * 2048 + kg + scol);
            }
        }

        s16x4 pf[2][4];
        #pragma unroll
        for (int kf = 0; kf < 4; ++kf) {
            const bf16_t* krow = &Kt[buf][g][(kf * 16 + l15) * 64];
            bf16x8 k0 = *(const bf16x8*)(krow + ksw0);
            bf16x8 k1 = *(const bf16x8*)(krow + ksw1);
            #pragma unroll
            for (int mt = 0; mt < 2; ++mt) {
                floatx4 z = {0.f, 0.f, 0.f, 0.f};
                z = mfma16(k0, aq[mt][0], z);
                z = mfma16(k1, aq[mt][1], z);
                bf16x4 pk;
                float s = 0.f;
                #pragma unroll
                for (int r = 0; r < 4; ++r) {
                    const float p = __builtin_amdgcn_exp2f(z[r]);
                    s += p;
                    pk[r] = (bf16_t)p;
                }
                rs[mt] += s;
                pf[mt][kf] = __builtin_bit_cast(s16x4, pk);
            }
        }

        #pragma unroll
        for (int kg2 = 0; kg2 < 4; ++kg2) {
            const int voff = (((kg2 * 2 + (quad >> 1)) ^ (l15 & 7)) * 8) + (quad & 1) * 4;
            #pragma unroll
            for (int df = 0; df < 4; ++df) {
                const s16x4 v = *(const s16x4*)(&Vt[buf][g][(df * 16 + l15) * 64 + voff]);
                #pragma unroll
                for (int mt = 0; mt < 2; ++mt)
                    O[mt][df] = mfma16k16(pf[mt][kg2], v, O[mt][df]);
            }
        }
    }

    #pragma unroll
    for (int mt = 0; mt < 2; ++mt) {
        rs[mt] += __shfl_xor(rs[mt], 16, 64);
        rs[mt] += __shfl_xor(rs[mt], 32, 64);
    }

    float* scratch = (float*)&Kt[0][0][0];
    __syncthreads();
    if (g == 1) {
        float* s = scratch + (size_t)(wq * 64 + lane) * 35;
        #pragma unroll
        for (int mt = 0; mt < 2; ++mt) {
            #pragma unroll
            for (int df = 0; df < 4; ++df)
                #pragma unroll
                for (int r = 0; r < 4; ++r) s[mt * 16 + df * 4 + r] = O[mt][df][r];
            s[32 + mt] = rs[mt];
        }
    }
    __syncthreads();
    if (g == 0) {
        const float* s = scratch + (size_t)(wq * 64 + lane) * 35;
        #pragma unroll
        for (int mt = 0; mt < 2; ++mt) {
            #pragma unroll
            for (int df = 0; df < 4; ++df)
                #pragma unroll
                for (int r = 0; r < 4; ++r) O[mt][df][r] += s[mt * 16 + df * 4 + r];
            rs[mt] += s[32 + mt];
        }

        const int b = bh >> 3, h = bh & 7;
        #pragma unroll
        for (int mt = 0; mt < 2; ++mt)
            #pragma unroll
            for (int r = 0; r < 4; ++r) {
                const float rv = __shfl(rs[mt], (quad << 4) + ((quad & 3) << 2) + r, 64);
                const float rinv = 1.0f / rv;
                const int s_ = qt * 64 + wq * 32 + mt * 16 + quad * 4 + r;
                const int sw = ((s_ >> 1) & 3) << 3;
                const size_t base = ((size_t)b * 2048 + s_) * 512;
                #pragma unroll
                for (int df = 0; df < 4; ++df) {
                    const int col = h * 64 + df * 16 + l15;
                    attn_ws[base + (col ^ sw)] = (bf16_t)(O[mt][df][r] * rinv);
                }
            }
    }
}

// ---------------------------------------------------------------------------
// Kernel 3: output projection — PROBE: body x2 (idempotent).
// ---------------------------------------------------------------------------
__global__ __launch_bounds__(256)
void out_proj(const bf16_t* __restrict__ attn_ws, const bf16_t* __restrict__ wob,
              const float* __restrict__ bo, float* __restrict__ y)
{
    __shared__ bf16_t As[2][64 * 32];
    __shared__ bf16_t Bs[2][128 * 32];

    const int mtile = blockIdx.x;
    const int ntile = blockIdx.y;
    const int tid = threadIdx.x, lane = tid & 63, wave = tid >> 6;
    const int wm = wave & 1, wn = wave >> 1;
    const int l15 = lane & 15, quad = lane >> 4;
    const int m0 = mtile * 64;
    const int n0 = ntile * 128;
    const int lr = lane >> 2, lc = (lane & 3) * 8;
    const int csw = (quad ^ ((l15 >> 1) & 3)) * 8;

    for (int rep = 0; rep < 2; ++rep) {
        floatx4 acc[2][4] = {};

        __syncthreads();
        {
            glds16(&As[0][wave * 16 * 32], attn_ws + (size_t)(m0 + wave * 16 + lr) * 512 + lc);
            #pragma unroll
            for (int q = 0; q < 2; ++q) {
                const int r = wave * 32 + q * 16;
                glds16(&Bs[0][r * 32], wob + (size_t)(n0 + r + lr) * 512 + lc);
            }
        }

        for (int kk = 0; kk < 16; ++kk) {
            const int buf = kk & 1;
            __syncthreads();
            if (kk < 15) {
                const int kn = (kk + 1) * 32;
                glds16(&As[buf ^ 1][wave * 16 * 32],
                       attn_ws + (size_t)(m0 + wave * 16 + lr) * 512 + kn + lc);
                #pragma unroll
                for (int q = 0; q < 2; ++q) {
                    const int r = wave * 32 + q * 16;
                    glds16(&Bs[buf ^ 1][r * 32], wob + (size_t)(n0 + r + lr) * 512 + kn + lc);
                }
            }

            bf16x8 af[2], bfr[4];
            #pragma unroll
            for (int i = 0; i < 2; ++i)
                af[i] = *(const bf16x8*)(&As[buf][(wm * 32 + i * 16 + l15) * 32 + csw]);
            #pragma unroll
            for (int j = 0; j < 4; ++j)
                bfr[j] = *(const bf16x8*)(&Bs[buf][(wn * 64 + j * 16 + l15) * 32 + csw]);
            #pragma unroll
            for (int i = 0; i < 2; ++i)
                #pragma unroll
                for (int j = 0; j < 4; ++j)
                    acc[i][j] = mfma16(af[i], bfr[j], acc[i][j]);
        }

        #pragma unroll
        for (int j = 0; j < 4; ++j) {
            const int e = n0 + wn * 64 + j * 16 + l15;
            const float be = bo[e];
            #pragma unroll
            for (int i = 0; i < 2; ++i) {
                const int mb = m0 + wm * 32 + i * 16 + quad * 4;
                #pragma unroll
                for (int r = 0; r < 4; ++r)
                    y[(size_t)(mb + r) * 512 + e] = acc[i][j][r] + be;
            }
        }
    }
}

// ---------------------------------------------------------------------------
extern "C" void kernel_launch(void* const* d_in, const int* in_sizes, int n_in,
                              void* d_out, int out_size, void* d_ws, size_t ws_size,
                              hipStream_t stream) {
    (void)in_sizes; (void)n_in; (void)out_size; (void)ws_size;
    const float* x  = (const float*)d_in[0];
    const float* Wq = (const float*)d_in[1];
    const float* bq = (const float*)d_in[2];
    const float* Wk = (const float*)d_in[3];
    const float* bk = (const float*)d_in[4];
    const float* Wv = (const float*)d_in[5];
    const float* bv = (const float*)d_in[6];
    const float* Wo = (const float*)d_in[7];
    const float* bo = (const float*)d_in[8];

    bf16_t* xb   = (bf16_t*)d_ws;
    bf16_t* wqb  = xb   + (size_t)MTOT * D_MODEL;
    bf16_t* wkb  = wqb  + (size_t)D_MODEL * D_MODEL;
    bf16_t* wvb  = wkb  + (size_t)D_MODEL * D_MODEL;
    bf16_t* wob  = wvb  + (size_t)D_MODEL * D_MODEL;
    bf16_t* qws  = wob  + (size_t)D_MODEL * D_MODEL;
    bf16_t* kws  = qws  + (size_t)MTOT * D_MODEL;
    bf16_t* vtws = kws  + (size_t)MTOT * D_MODEL;
    bf16_t* aws  = vtws + (size_t)MTOT * D_MODEL;

    to_bf16    <<<1536, 256, 0, stream>>>(x, Wq, Wk, Wv, Wo, xb, wqb, wkb, wvb, wob);
    qkv_proj   <<<dim3(64, 12), 256, 0, stream>>>(xb, wqb, bq, wkb, bk, wvb, bv, qws, kws, vtws);
    attn_kernel<<<dim3(16, 32), 256, 0, stream>>>(qws, kws, vtws, aws);
    out_proj   <<<dim3(64, 4),  256, 0, stream>>>(aws, wob, bo, (float*)d_out);
}

// Round 12
// 132.642 us; speedup vs baseline: 1.2039x; 1.2039x over previous
//
#include <hip/hip_runtime.h>

typedef __bf16 bf16_t;
typedef bf16_t bf16x8 __attribute__((ext_vector_type(8)));
typedef bf16_t bf16x4 __attribute__((ext_vector_type(4)));
typedef float  floatx4 __attribute__((ext_vector_type(4)));
typedef short  s16x4   __attribute__((ext_vector_type(4)));

#define D_MODEL 512
#define NHEAD   8
#define DK      64
#define BATCH   2
#define SEQ     2048
#define MTOT    (BATCH*SEQ)     /* 4096 */
#define QSCALE  0.18033688011112042591f  /* log2(e)/8 */

static __device__ __forceinline__ floatx4 mfma16(bf16x8 a, bf16x8 b, floatx4 c) {
    return __builtin_amdgcn_mfma_f32_16x16x32_bf16(a, b, c, 0, 0, 0);
}
// K=16 MFMA: A-operand layout k = quad*4+j == 16x16 C-layout rows -> P stays in regs
static __device__ __forceinline__ floatx4 mfma16k16(s16x4 a, s16x4 b, floatx4 c) {
    return __builtin_amdgcn_mfma_f32_16x16x16bf16_1k(a, b, c, 0, 0, 0);
}
static __device__ __forceinline__ void glds16(bf16_t* lds, const bf16_t* g) {
    __builtin_amdgcn_global_load_lds(
        (const __attribute__((address_space(1))) unsigned int*)g,
        (__attribute__((address_space(3))) unsigned int*)lds,
        16, 0, 0);
}
static __device__ __forceinline__ bf16x8 cvt8(float4 a, float4 b) {
    bf16x8 p;
    p[0]=(bf16_t)a.x; p[1]=(bf16_t)a.y; p[2]=(bf16_t)a.z; p[3]=(bf16_t)a.w;
    p[4]=(bf16_t)b.x; p[5]=(bf16_t)b.y; p[6]=(bf16_t)b.z; p[7]=(bf16_t)b.w;
    return p;
}

// ---------------------------------------------------------------------------
// Kernel 1: fused QKV projection, fp32 inputs, register-prefetch (dist-2)
// staging + in-register cvt + swizzled ds_write.  Same LDS images, fragment
// reads, and epilogue as R7.  64x128 tile, grid (64,12).
// ---------------------------------------------------------------------------
__global__ __launch_bounds__(256)
void qkv_proj(const float* __restrict__ x,
              const float* __restrict__ Wq, const float* __restrict__ bq,
              const float* __restrict__ Wk, const float* __restrict__ bk,
              const float* __restrict__ Wv, const float* __restrict__ bv,
              bf16_t* __restrict__ q_ws, bf16_t* __restrict__ k_ws,
              bf16_t* __restrict__ vt_ws)
{
    __shared__ bf16_t As[2][64 * 32];
    __shared__ bf16_t Bs[2][128 * 32];

    const int mtile = blockIdx.x;
    const int ntile = blockIdx.y;
    const int which = ntile >> 2;
    const int nsub  = ntile & 3;
    const float* W    = (which == 0) ? Wq : (which == 1) ? Wk : Wv;
    const float* bias = (which == 0) ? bq : (which == 1) ? bk : bv;

    const int tid  = threadIdx.x;
    const int lane = tid & 63;
    const int wave = tid >> 6;
    const int wm = wave & 1, wn = wave >> 1;
    const int l15 = lane & 15, quad = lane >> 4;
    const int m0 = mtile * 64;
    const int n0 = nsub * 128;
    const int csw = (quad ^ ((l15 >> 1) & 3)) * 8;

    // staging coords: A 64x32 (8 fp32/thread), B 128x32 (16 fp32/thread)
    const int arow = tid >> 2, aseg = tid & 3;
    const int brow = tid >> 1, bsg0 = (tid & 1) * 2;   // chunks bsg0, bsg0+1
    const int aswz = (arow >> 1) & 3;
    const int bswz = (brow >> 1) & 3;
    const float* pa = x + (size_t)(m0 + arow) * 512 + aseg * 8;
    const float* pb = W + (size_t)(n0 + brow) * 512 + bsg0 * 8;

    float4 ra[2][2], rb[2][4];
    #pragma unroll
    for (int bank = 0; bank < 2; ++bank) {      // preload slices 0,1
        const int k0 = bank * 32;
        ra[bank][0] = *(const float4*)(pa + k0);
        ra[bank][1] = *(const float4*)(pa + k0 + 4);
        rb[bank][0] = *(const float4*)(pb + k0);
        rb[bank][1] = *(const float4*)(pb + k0 + 4);
        rb[bank][2] = *(const float4*)(pb + k0 + 8);
        rb[bank][3] = *(const float4*)(pb + k0 + 12);
    }

    floatx4 acc[2][4] = {};

    for (int kk = 0; kk < 16; ++kk) {
        const int buf = kk & 1;
        // cvt + swizzled ds_write of slice kk from its register bank
        *(bf16x8*)(&As[buf][arow * 32 + (aseg ^ aswz) * 8]) =
            cvt8(ra[buf][0], ra[buf][1]);
        *(bf16x8*)(&Bs[buf][brow * 32 + (bsg0 ^ bswz) * 8]) =
            cvt8(rb[buf][0], rb[buf][1]);
        *(bf16x8*)(&Bs[buf][brow * 32 + ((bsg0 + 1) ^ bswz) * 8]) =
            cvt8(rb[buf][2], rb[buf][3]);
        __syncthreads();
        if (kk < 14) {                           // prefetch slice kk+2
            const int k0 = (kk + 2) * 32;
            ra[buf][0] = *(const float4*)(pa + k0);
            ra[buf][1] = *(const float4*)(pa + k0 + 4);
            rb[buf][0] = *(const float4*)(pb + k0);
            rb[buf][1] = *(const float4*)(pb + k0 + 4);
            rb[buf][2] = *(const float4*)(pb + k0 + 8);
            rb[buf][3] = *(const float4*)(pb + k0 + 12);
        }

        bf16x8 af[2], bfr[4];
        #pragma unroll
        for (int i = 0; i < 2; ++i)
            af[i] = *(const bf16x8*)(&As[buf][(wm * 32 + i * 16 + l15) * 32 + csw]);
        #pragma unroll
        for (int j = 0; j < 4; ++j)
            bfr[j] = *(const bf16x8*)(&Bs[buf][(wn * 64 + j * 16 + l15) * 32 + csw]);
        #pragma unroll
        for (int i = 0; i < 2; ++i)
            #pragma unroll
            for (int j = 0; j < 4; ++j)
                acc[i][j] = mfma16(af[i], bfr[j], acc[i][j]);
        __syncthreads();   // all reads of buf done before its rewrite at kk+2
    }

    #pragma unroll
    for (int j = 0; j < 4; ++j) {
        const int e = n0 + wn * 64 + j * 16 + l15;
        const float be = bias[e];
        const int h = e >> 6, d = e & 63;
        #pragma unroll
        for (int i = 0; i < 2; ++i) {
            const int mbase = m0 + wm * 32 + i * 16 + quad * 4;
            const int b = mbase >> 11;
            const int sl = mbase & 2047;
            floatx4 c = acc[i][j];
            if (which == 2) {
                bf16x4 pk;
                #pragma unroll
                for (int r = 0; r < 4; ++r) pk[r] = (bf16_t)(c[r] + be);
                const int slz = (sl & ~63) | ((((sl >> 3) & 7) ^ (d & 7)) << 3) | (sl & 7);
                *(bf16x4*)(vt_ws + ((size_t)((b * 8 + h) * 64 + d)) * 2048 + slz) = pk;
            } else if (which == 1) {
                #pragma unroll
                for (int r = 0; r < 4; ++r) {
                    const int s = sl + r;
                    const int dz = ((((d >> 3) ^ (s & 7))) << 3) | (d & 7);
                    k_ws[(size_t)(b * 8 + h) * (SEQ * DK) + (size_t)s * 64 + dz] =
                        (bf16_t)(c[r] + be);
                }
            } else {
                #pragma unroll
                for (int r = 0; r < 4; ++r)
                    q_ws[(size_t)(b * 8 + h) * (SEQ * DK) + (size_t)(sl + r) * 64 + d] =
                        (bf16_t)((c[r] + be) * QSCALE);
            }
        }
    }
}

// ---------------------------------------------------------------------------
// Kernel 2: attention — R7 body, byte-identical.
// ---------------------------------------------------------------------------
__global__ __launch_bounds__(256, 2)
void attn_kernel(const bf16_t* __restrict__ q_ws, const bf16_t* __restrict__ k_ws,
                 const bf16_t* __restrict__ vt_ws, bf16_t* __restrict__ attn_ws)
{
    __shared__ bf16_t Kt[2][2][64 * 64];
    __shared__ bf16_t Vt[2][2][64 * 64];

    const int bh = blockIdx.x;
    const int qt = blockIdx.y;
    const int tid = threadIdx.x, lane = tid & 63, wave = tid >> 6;
    const int l15 = lane & 15, quad = lane >> 4;
    const int g  = wave >> 1;
    const int wq = wave & 1;

    const bf16_t* Qb  = q_ws  + (size_t)bh * SEQ * DK;
    const bf16_t* Kb  = k_ws  + (size_t)bh * SEQ * DK;
    const bf16_t* Vtb = vt_ws + (size_t)bh * DK * SEQ;

    const int sp = wave & 1;
    const bool isK = wave < 2;
    const int srow8 = lane >> 3;
    const int scol  = (lane & 7) * 8;

    bf16x8 aq[2][2];
    #pragma unroll
    for (int mt = 0; mt < 2; ++mt)
        #pragma unroll
        for (int c = 0; c < 2; ++c)
            aq[mt][c] = *(const bf16x8*)(Qb +
                (size_t)(qt * 64 + wq * 32 + mt * 16 + l15) * 64 + c * 32 + quad * 8);

    floatx4 O[2][4] = {};
    float rs[2] = {0.f, 0.f};
    const int ksw0 = ((0 + quad) ^ (l15 & 7)) * 8;
    const int ksw1 = ((4 + quad) ^ (l15 & 7)) * 8;

    {
        const int kg = sp * 64;
        bf16_t* stile = isK ? &Kt[0][sp][0] : &Vt[0][sp][0];
        if (isK) {
            #pragma unroll
            for (int i = 0; i < 8; ++i)
                glds16(stile + i * 512, Kb + (size_t)(kg + i * 8 + srow8) * 64 + scol);
        } else {
            #pragma unroll
            for (int i = 0; i < 8; ++i)
                glds16(stile + i * 512, Vtb + (size_t)(i * 8 + srow8) * 2048 + kg + scol);
        }
    }

    for (int t = 0; t < 16; ++t) {
        const int buf = t & 1;
        __syncthreads();
        if (t < 15) {
            const int kg = (t + 1) * 128 + sp * 64;
            bf16_t* stile = isK ? &Kt[buf ^ 1][sp][0] : &Vt[buf ^ 1][sp][0];
            if (isK) {
                #pragma unroll
                for (int i = 0; i < 8; ++i)
                    glds16(stile + i * 512, Kb + (size_t)(kg + i * 8 + srow8) * 64 + scol);
            } else {
                #pragma unroll
                for (int i = 0; i < 8; ++i)
                    glds16(stile + i * 512, Vtb + (size_t)(i * 8 + srow8) * 2048 + kg + scol);
            }
        }

        s16x4 pf[2][4];
        #pragma unroll
        for (int kf = 0; kf < 4; ++kf) {
            const bf16_t* krow = &Kt[buf][g][(kf * 16 + l15) * 64];
            bf16x8 k0 = *(const bf16x8*)(krow + ksw0);
            bf16x8 k1 = *(const bf16x8*)(krow + ksw1);
            #pragma unroll
            for (int mt = 0; mt < 2; ++mt) {
                floatx4 z = {0.f, 0.f, 0.f, 0.f};
                z = mfma16(k0, aq[mt][0], z);
                z = mfma16(k1, aq[mt][1], z);
                bf16x4 pk;
                float s = 0.f;
                #pragma unroll
                for (int r = 0; r < 4; ++r) {
                    const float p = __builtin_amdgcn_exp2f(z[r]);
                    s += p;
                    pk[r] = (bf16_t)p;
                }
                rs[mt] += s;
                pf[mt][kf] = __builtin_bit_cast(s16x4, pk);
            }
        }

        #pragma unroll
        for (int kg2 = 0; kg2 < 4; ++kg2) {
            const int voff = (((kg2 * 2 + (quad >> 1)) ^ (l15 & 7)) * 8) + (quad & 1) * 4;
            #pragma unroll
            for (int df = 0; df < 4; ++df) {
                const s16x4 v = *(const s16x4*)(&Vt[buf][g][(df * 16 + l15) * 64 + voff]);
                #pragma unroll
                for (int mt = 0; mt < 2; ++mt)
                    O[mt][df] = mfma16k16(pf[mt][kg2], v, O[mt][df]);
            }
        }
    }

    #pragma unroll
    for (int mt = 0; mt < 2; ++mt) {
        rs[mt] += __shfl_xor(rs[mt], 16, 64);
        rs[mt] += __shfl_xor(rs[mt], 32, 64);
    }

    float* scratch = (float*)&Kt[0][0][0];
    __syncthreads();
    if (g == 1) {
        float* s = scratch + (size_t)(wq * 64 + lane) * 35;
        #pragma unroll
        for (int mt = 0; mt < 2; ++mt) {
            #pragma unroll
            for (int df = 0; df < 4; ++df)
                #pragma unroll
                for (int r = 0; r < 4; ++r) s[mt * 16 + df * 4 + r] = O[mt][df][r];
            s[32 + mt] = rs[mt];
        }
    }
    __syncthreads();
    if (g == 0) {
        const float* s = scratch + (size_t)(wq * 64 + lane) * 35;
        #pragma unroll
        for (int mt = 0; mt < 2; ++mt) {
            #pragma unroll
            for (int df = 0; df < 4; ++df)
                #pragma unroll
                for (int r = 0; r < 4; ++r) O[mt][df][r] += s[mt * 16 + df * 4 + r];
            rs[mt] += s[32 + mt];
        }

        const int b = bh >> 3, h = bh & 7;
        #pragma unroll
        for (int mt = 0; mt < 2; ++mt)
            #pragma unroll
            for (int r = 0; r < 4; ++r) {
                const float rv = __shfl(rs[mt], (quad << 4) + ((quad & 3) << 2) + r, 64);
                const float rinv = 1.0f / rv;
                const int s_ = qt * 64 + wq * 32 + mt * 16 + quad * 4 + r;
                const int sw = ((s_ >> 1) & 3) << 3;
                const size_t base = ((size_t)b * 2048 + s_) * 512;
                #pragma unroll
                for (int df = 0; df < 4; ++df) {
                    const int col = h * 64 + df * 16 + l15;
                    attn_ws[base + (col ^ sw)] = (bf16_t)(O[mt][df][r] * rinv);
                }
            }
    }
}

// ---------------------------------------------------------------------------
// Kernel 3: output projection.  A = attn_ws (bf16, pre-swizzled image),
// B = Wo (fp32, cvt in-register).  Dist-2 register staging, same reads/epilogue.
// ---------------------------------------------------------------------------
__global__ __launch_bounds__(256)
void out_proj(const bf16_t* __restrict__ attn_ws, const float* __restrict__ Wo,
              const float* __restrict__ bo, float* __restrict__ y)
{
    __shared__ bf16_t As[2][64 * 32];
    __shared__ bf16_t Bs[2][128 * 32];

    const int mtile = blockIdx.x;
    const int ntile = blockIdx.y;
    const int tid = threadIdx.x, lane = tid & 63, wave = tid >> 6;
    const int wm = wave & 1, wn = wave >> 1;
    const int l15 = lane & 15, quad = lane >> 4;
    const int m0 = mtile * 64;
    const int n0 = ntile * 128;
    const int csw = (quad ^ ((l15 >> 1) & 3)) * 8;

    const int arow = tid >> 2, aseg = tid & 3;
    const int brow = tid >> 1, bsg0 = (tid & 1) * 2;
    const int bswz = (brow >> 1) & 3;
    const bf16_t* pa = attn_ws + (size_t)(m0 + arow) * 512 + aseg * 8;
    const float*  pb = Wo + (size_t)(n0 + brow) * 512 + bsg0 * 8;

    bf16x8 ra[2];
    float4 rb[2][4];
    #pragma unroll
    for (int bank = 0; bank < 2; ++bank) {
        const int k0 = bank * 32;
        ra[bank] = *(const bf16x8*)(pa + k0);
        rb[bank][0] = *(const float4*)(pb + k0);
        rb[bank][1] = *(const float4*)(pb + k0 + 4);
        rb[bank][2] = *(const float4*)(pb + k0 + 8);
        rb[bank][3] = *(const float4*)(pb + k0 + 12);
    }

    floatx4 acc[2][4] = {};

    for (int kk = 0; kk < 16; ++kk) {
        const int buf = kk & 1;
        // A image is pre-swizzled in global; write linear.
        *(bf16x8*)(&As[buf][arow * 32 + aseg * 8]) = ra[buf];
        *(bf16x8*)(&Bs[buf][brow * 32 + (bsg0 ^ bswz) * 8]) =
            cvt8(rb[buf][0], rb[buf][1]);
        *(bf16x8*)(&Bs[buf][brow * 32 + ((bsg0 + 1) ^ bswz) * 8]) =
            cvt8(rb[buf][2], rb[buf][3]);
        __syncthreads();
        if (kk < 14) {
            const int k0 = (kk + 2) * 32;
            ra[buf] = *(const bf16x8*)(pa + k0);
            rb[buf][0] = *(const float4*)(pb + k0);
            rb[buf][1] = *(const float4*)(pb + k0 + 4);
            rb[buf][2] = *(const float4*)(pb + k0 + 8);
            rb[buf][3] = *(const float4*)(pb + k0 + 12);
        }

        bf16x8 af[2], bfr[4];
        #pragma unroll
        for (int i = 0; i < 2; ++i)
            af[i] = *(const bf16x8*)(&As[buf][(wm * 32 + i * 16 + l15) * 32 + csw]);
        #pragma unroll
        for (int j = 0; j < 4; ++j)
            bfr[j] = *(const bf16x8*)(&Bs[buf][(wn * 64 + j * 16 + l15) * 32 + csw]);
        #pragma unroll
        for (int i = 0; i < 2; ++i)
            #pragma unroll
            for (int j = 0; j < 4; ++j)
                acc[i][j] = mfma16(af[i], bfr[j], acc[i][j]);
        __syncthreads();
    }

    #pragma unroll
    for (int j = 0; j < 4; ++j) {
        const int e = n0 + wn * 64 + j * 16 + l15;
        const float be = bo[e];
        #pragma unroll
        for (int i = 0; i < 2; ++i) {
            const int mb = m0 + wm * 32 + i * 16 + quad * 4;
            #pragma unroll
            for (int r = 0; r < 4; ++r)
                y[(size_t)(mb + r) * 512 + e] = acc[i][j][r] + be;
        }
    }
}

// ---------------------------------------------------------------------------
extern "C" void kernel_launch(void* const* d_in, const int* in_sizes, int n_in,
                              void* d_out, int out_size, void* d_ws, size_t ws_size,
                              hipStream_t stream) {
    (void)in_sizes; (void)n_in; (void)out_size; (void)ws_size;
    const float* x  = (const float*)d_in[0];
    const float* Wq = (const float*)d_in[1];
    const float* bq = (const float*)d_in[2];
    const float* Wk = (const float*)d_in[3];
    const float* bk = (const float*)d_in[4];
    const float* Wv = (const float*)d_in[5];
    const float* bv = (const float*)d_in[6];
    const float* Wo = (const float*)d_in[7];
    const float* bo = (const float*)d_in[8];

    bf16_t* qws  = (bf16_t*)d_ws;
    bf16_t* kws  = qws  + (size_t)MTOT * D_MODEL;
    bf16_t* vtws = kws  + (size_t)MTOT * D_MODEL;
    bf16_t* aws  = vtws + (size_t)MTOT * D_MODEL;

    qkv_proj   <<<dim3(64, 12), 256, 0, stream>>>(x, Wq, bq, Wk, bk, Wv, bv, qws, kws, vtws);
    attn_kernel<<<dim3(16, 32), 256, 0, stream>>>(qws, kws, vtws, aws);
    out_proj   <<<dim3(64, 4),  256, 0, stream>>>(aws, Wo, bo, (float*)d_out);
}